// Round 2
// baseline (226.173 us; speedup 1.0000x reference)
//
#include <hip/hip_runtime.h>

#define BATCH 16
#define NANCH 8400
#define MGT 32
#define NCLS 80
#define RCH 64
#define NCH 144
#define TOPKK 10
#define NEGV -100000000.0f

struct AInfo { int lvl, pos, W, HW; float s, ax, ay; };

__device__ __forceinline__ AInfo anchor_of(int n) {
  AInfo a;
  if (n < 6400)      { a.lvl = 0; a.pos = n;        a.W = 80; a.HW = 6400; a.s = 8.f;  }
  else if (n < 8000) { a.lvl = 1; a.pos = n - 6400; a.W = 40; a.HW = 1600; a.s = 16.f; }
  else               { a.lvl = 2; a.pos = n - 8000; a.W = 20; a.HW = 400;  a.s = 32.f; }
  int px = a.pos % a.W, py = a.pos / a.W;
  a.ax = (px + 0.5f) * a.s;
  a.ay = (py + 0.5f) * a.s;
  return a;
}

__device__ __forceinline__ const float* lvl_ptr(const float* p0, const float* p1,
                                                const float* p2, int lvl) {
  return lvl == 0 ? p0 : (lvl == 1 ? p1 : p2);
}

__device__ __forceinline__ float iou_xyxy(float4 a, float4 b) {
  float ix = fmaxf(fminf(a.z, b.z) - fmaxf(a.x, b.x), 0.f);
  float iy = fmaxf(fminf(a.w, b.w) - fmaxf(a.y, b.y), 0.f);
  float inter = ix * iy;
  float w1 = fmaxf(a.z - a.x, 0.f), h1 = fmaxf(a.w - a.y, 0.f);
  float w2 = fmaxf(b.z - b.x, 0.f), h2 = fmaxf(b.w - b.y, 0.f);
  float uni = w1 * h1 + w2 * h2 - inter + 1e-7f;
  return inter / uni;
}

__device__ __forceinline__ float ciou_xyxy(float4 a, float4 b) {
  const float eps = 1e-7f;
  float ix = fmaxf(fminf(a.z, b.z) - fmaxf(a.x, b.x), 0.f);
  float iy = fmaxf(fminf(a.w, b.w) - fmaxf(a.y, b.y), 0.f);
  float inter = ix * iy;
  float w1 = fmaxf(a.z - a.x, 0.f), h1 = fmaxf(a.w - a.y, 0.f);
  float w2 = fmaxf(b.z - b.x, 0.f), h2 = fmaxf(b.w - b.y, 0.f);
  float uni = w1 * h1 + w2 * h2 - inter + eps;
  float iou = inter / uni;
  float cx1 = (a.x + a.z) * 0.5f, cy1 = (a.y + a.w) * 0.5f;
  float cx2 = (b.x + b.z) * 0.5f, cy2 = (b.y + b.w) * 0.5f;
  float rho2 = (cx2 - cx1) * (cx2 - cx1) + (cy2 - cy1) * (cy2 - cy1);
  float cw = fmaxf(a.z, b.z) - fminf(a.x, b.x);
  float ch = fmaxf(a.w, b.w) - fminf(a.y, b.y);
  float c2 = cw * cw + ch * ch + eps;
  const float kpi = 4.f / (float)(M_PI * M_PI);
  float dat = atanf(w2 / (h2 + eps)) - atanf(w1 / (h1 + eps));
  float v = kpi * dat * dat;
  float alpha = v / (1.f - iou + v + eps);
  return iou - (rho2 / c2 + alpha * v);
}

__device__ __forceinline__ float block_sum256(float v) {
  __shared__ float sm[4];
  #pragma unroll
  for (int off = 32; off; off >>= 1) v += __shfl_xor(v, off);
  __syncthreads();
  if ((threadIdx.x & 63) == 0) sm[threadIdx.x >> 6] = v;
  __syncthreads();
  return (threadIdx.x == 0) ? (sm[0] + sm[1] + sm[2] + sm[3]) : 0.f;
}

// --- K0: zero the accumulators ---------------------------------------------
__global__ void k_zero(double* accum) {
  if (threadIdx.x < 8) accum[threadIdx.x] = 0.0;
}

// --- A: decode pred boxes, sum BCE base term, zero the argmax slots --------
__global__ __launch_bounds__(256) void k_decode(
    const float* __restrict__ p0, const float* __restrict__ p1, const float* __restrict__ p2,
    float4* __restrict__ pbox, unsigned long long* __restrict__ slots,
    double* __restrict__ accum) {
  int i = blockIdx.x * 256 + threadIdx.x;   // exact: 525*256 == 16*8400
  slots[i] = 0ULL;
  int b = i / NANCH, n = i % NANCH;
  AInfo A = anchor_of(n);
  const float* p = lvl_ptr(p0, p1, p2, A.lvl);
  size_t base = (size_t)b * NCH * A.HW + A.pos;

  float dist[4];
  #pragma unroll
  for (int sd = 0; sd < 4; ++sd) {
    float z[16]; float zm = -1e30f;
    #pragma unroll
    for (int j = 0; j < 16; ++j) {
      z[j] = p[base + (size_t)(sd * 16 + j) * A.HW];
      zm = fmaxf(zm, z[j]);
    }
    float se = 0.f, ae = 0.f;
    #pragma unroll
    for (int j = 0; j < 16; ++j) {
      float e = expf(z[j] - zm);
      se += e; ae += e * (float)j;
    }
    dist[sd] = ae / se * A.s;
  }
  pbox[i] = make_float4(A.ax - dist[0], A.ay - dist[1], A.ax + dist[2], A.ay + dist[3]);

  float lb = 0.f;
  for (int c = 0; c < NCLS; ++c) {
    float z = p[base + (size_t)(RCH + c) * A.HW];
    lb += fmaxf(z, 0.f) + log1pf(expf(-fabsf(z)));
  }
  float tot = block_sum256(lb);
  if (threadIdx.x == 0) atomicAdd(&accum[0], (double)tot);
}

// --- B: per-(b,gt) align + top-10 selection + metric_max -------------------
__global__ __launch_bounds__(256) void k_topk(
    const float* __restrict__ p0, const float* __restrict__ p1, const float* __restrict__ p2,
    const float4* __restrict__ pbox, const float* __restrict__ gtb, const int* __restrict__ gtl,
    float* __restrict__ metric_max, int* __restrict__ topk) {
  __shared__ float a[NANCH];
  __shared__ float rv[4];
  __shared__ int   ri[4];
  int b = blockIdx.x >> 5, m = blockIdx.x & 31;
  int tid = threadIdx.x;
  float4 g = ((const float4*)gtb)[b * MGT + m];
  int gl = min(max(gtl[b * MGT + m], 0), NCLS - 1);

  for (int n = tid; n < NANCH; n += 256) {
    AInfo A = anchor_of(n);
    float l = A.ax - g.x, t = A.ay - g.y, r = g.z - A.ax, bo = g.w - A.ay;
    float al = NEGV;
    if (l > 0.f && t > 0.f && r > 0.f && bo > 0.f) {
      float iou = iou_xyxy(pbox[b * NANCH + n], g);
      const float* p = lvl_ptr(p0, p1, p2, A.lvl);
      float z = p[(size_t)b * NCH * A.HW + (size_t)(RCH + gl) * A.HW + A.pos];
      float sg = 1.f / (1.f + expf(-z));
      float i3 = iou * iou * iou;
      al = sqrtf(sg) * i3 * i3;
    }
    a[n] = al;
  }
  __syncthreads();

  float mmax = NEGV;
  for (int k = 0; k < TOPKK; ++k) {
    float bv = -3e38f; int bi = 0x7fffffff;
    for (int n = tid; n < NANCH; n += 256) {
      float v = a[n];
      if (v > bv) { bv = v; bi = n; }     // strict > keeps lowest index (ascending scan)
    }
    #pragma unroll
    for (int off = 32; off; off >>= 1) {
      float ov = __shfl_xor(bv, off);
      int   oi = __shfl_xor(bi, off);
      if (ov > bv || (ov == bv && oi < bi)) { bv = ov; bi = oi; }
    }
    if ((tid & 63) == 0) { rv[tid >> 6] = bv; ri[tid >> 6] = bi; }
    __syncthreads();
    if (tid == 0) {
      #pragma unroll
      for (int w = 1; w < 4; ++w)
        if (rv[w] > bv || (rv[w] == bv && ri[w] < bi)) { bv = rv[w]; bi = ri[w]; }
      topk[(b * MGT + m) * TOPKK + k] = (bv >= 0.f) ? bi : -1;   // valid <=> in_gts
      if (bv >= 0.f) mmax = fmaxf(mmax, bv);
      a[bi] = -3e38f;                                            // remove winner
    }
    __syncthreads();
  }
  if (tid == 0) metric_max[b * MGT + m] = fmaxf(mmax, 1e-9f);
}

// --- C: scatter top-k entries into per-anchor argmax-over-gt slots ---------
__global__ void k_scatter(const float4* __restrict__ pbox, const float* __restrict__ gtb,
                          const int* __restrict__ topk, unsigned long long* __restrict__ slots) {
  int e = blockIdx.x * 256 + threadIdx.x;
  if (e >= BATCH * MGT * TOPKK) return;
  int b = e / (MGT * TOPKK);
  int r = e % (MGT * TOPKK);
  int m = r / TOPKK;
  int n = topk[e];
  if (n < 0) return;
  float4 g = ((const float4*)gtb)[b * MGT + m];
  float iou = iou_xyxy(pbox[b * NANCH + n], g);
  // iou >= 0 so float bits are order-preserving; ties prefer smaller m (bigger 31-m)
  unsigned long long key = (1ULL << 62) |
                           ((unsigned long long)__float_as_uint(iou) << 6) |
                           (unsigned long long)(31 - m);
  atomicMax(&slots[b * NANCH + n], key);
}

// --- D: fg-anchor losses: score, bce correction, ciou, dfl -----------------
__global__ __launch_bounds__(256) void k_final(
    const float* __restrict__ p0, const float* __restrict__ p1, const float* __restrict__ p2,
    const float4* __restrict__ pbox, const float* __restrict__ gtb, const int* __restrict__ gtl,
    const float* __restrict__ metric_max, const unsigned long long* __restrict__ slots,
    double* __restrict__ accum) {
  int i = blockIdx.x * 256 + threadIdx.x;
  unsigned long long key = slots[i];
  float ts_p = 0.f, zc_p = 0.f, box_p = 0.f, dfl_p = 0.f;
  if (key) {
    int b = i / NANCH, n = i % NANCH;
    int m = 31 - (int)(key & 63ULL);
    float iou = __uint_as_float((unsigned int)((key >> 6) & 0xFFFFFFFFULL));
    AInfo A = anchor_of(n);
    float4 g = ((const float4*)gtb)[b * MGT + m];
    int gl = min(max(gtl[b * MGT + m], 0), NCLS - 1);
    const float* p = lvl_ptr(p0, p1, p2, A.lvl);
    size_t base = (size_t)b * NCH * A.HW + A.pos;

    float z = p[base + (size_t)(RCH + gl) * A.HW];
    float sg = 1.f / (1.f + expf(-z));
    float i3 = iou * iou * iou;
    float align = sqrtf(sg) * i3 * i3;
    float mm = metric_max[b * MGT + m];
    float score = fminf(fmaxf(align / mm * iou, 0.f), 1.f);

    ts_p = score;
    zc_p = z * score;

    float4 pb = pbox[i];
    float ciou = ciou_xyxy(pb, g);
    box_p = (1.f - ciou) * score;

    float inv_s = 1.f / A.s;
    float targ0 = (A.ax - g.x) * inv_s;
    float targ1 = (A.ay - g.y) * inv_s;
    float targ2 = (g.z - A.ax) * inv_s;
    float targ3 = (g.w - A.ay) * inv_s;
    float dfl = 0.f;
    #pragma unroll
    for (int sd = 0; sd < 4; ++sd) {
      float tg = sd == 0 ? targ0 : sd == 1 ? targ1 : sd == 2 ? targ2 : targ3;
      float t = fminf(fmaxf(tg, 0.f), 15.f);
      int left = (int)floorf(t);
      int right = min(left + 1, 15);
      float wl, wr;
      if (right == left) { wl = 1.f; wr = 0.f; }
      else               { wl = (float)right - t; wr = t - (float)left; }
      float zm = -1e30f, zl = 0.f, zr = 0.f;
      float zz[16];
      #pragma unroll
      for (int j = 0; j < 16; ++j) {
        zz[j] = p[base + (size_t)(sd * 16 + j) * A.HW];
        zm = fmaxf(zm, zz[j]);
      }
      float se = 0.f;
      #pragma unroll
      for (int j = 0; j < 16; ++j) {
        se += expf(zz[j] - zm);
        if (j == left)  zl = zz[j];   // compile-time j vs runtime left -> cndmask, no scratch
        if (j == right) zr = zz[j];
      }
      float logZ = zm + logf(se);
      dfl += wl * (logZ - zl) + wr * (logZ - zr);
    }
    dfl_p = dfl * score;
  }
  float s;
  s = block_sum256(ts_p);  if (threadIdx.x == 0 && s != 0.f) atomicAdd(&accum[4], (double)s);
  s = block_sum256(zc_p);  if (threadIdx.x == 0 && s != 0.f) atomicAdd(&accum[1], (double)s);
  s = block_sum256(box_p); if (threadIdx.x == 0 && s != 0.f) atomicAdd(&accum[2], (double)s);
  s = block_sum256(dfl_p); if (threadIdx.x == 0 && s != 0.f) atomicAdd(&accum[3], (double)s);
}

// --- E: combine ------------------------------------------------------------
__global__ void k_out(const double* __restrict__ accum, float* __restrict__ out) {
  double ts = fmax(accum[4], 1.0);
  double loss = 7.5 * accum[2] / ts +
                0.5 * (accum[0] - accum[1]) / ts +
                1.5 * accum[3] / ts;
  out[0] = (float)loss;
}

extern "C" void kernel_launch(void* const* d_in, const int* in_sizes, int n_in,
                              void* d_out, int out_size, void* d_ws, size_t ws_size,
                              hipStream_t stream) {
  const float* p0  = (const float*)d_in[0];
  const float* p1  = (const float*)d_in[1];
  const float* p2  = (const float*)d_in[2];
  const float* gtb = (const float*)d_in[3];
  const int*   gtl = (const int*)d_in[4];
  float* out = (float*)d_out;

  // Workspace layout (sizes in bytes, all non-overlapping, 16/8-aligned):
  //   accum      @ 0        : 8 * 8            = 64
  //   metric_max @ 64       : 512 * 4          = 2048   (ends 2112)
  //   topk       @ 2112     : 5120 * 4         = 20480  (ends 22592)
  //   pbox       @ 22592    : 134400 * 16      = 2150400 (ends 2172992)  [22592 % 16 == 0]
  //   slots      @ 2172992  : 134400 * 8       = 1075200 (ends 3248192)  [2172992 % 8 == 0]
  char* ws = (char*)d_ws;
  double* accum        = (double*)ws;
  float*  metric_max   = (float*)(ws + 64);
  int*    topk         = (int*)(ws + 2112);
  float4* pbox         = (float4*)(ws + 22592);
  unsigned long long* slots = (unsigned long long*)(ws + 2172992);

  k_zero<<<1, 64, 0, stream>>>(accum);
  k_decode<<<(BATCH * NANCH) / 256, 256, 0, stream>>>(p0, p1, p2, pbox, slots, accum);
  k_topk<<<BATCH * MGT, 256, 0, stream>>>(p0, p1, p2, pbox, gtb, gtl, metric_max, topk);
  k_scatter<<<(BATCH * MGT * TOPKK + 255) / 256, 256, 0, stream>>>(pbox, gtb, topk, slots);
  k_final<<<(BATCH * NANCH) / 256, 256, 0, stream>>>(p0, p1, p2, pbox, gtb, gtl,
                                                     metric_max, slots, accum);
  k_out<<<1, 1, 0, stream>>>(accum, out);
}

// Round 3
// 179.550 us; speedup vs baseline: 1.2597x; 1.2597x over previous
//
#include <hip/hip_runtime.h>

#define BATCH 16
#define NANCH 8400
#define MGT 32
#define NCLS 80
#define RCH 64
#define NCH 144
#define TOPKK 10
#define MAXC 576   // max in-box candidate cells: <=19^2 + 11^2 + 7^2 = 531

struct AInfo { int lvl, pos, W, HW; float s, ax, ay; };

__device__ __forceinline__ AInfo anchor_of(int n) {
  AInfo a;
  if (n < 6400)      { a.lvl = 0; a.pos = n;        a.W = 80; a.HW = 6400; a.s = 8.f;  }
  else if (n < 8000) { a.lvl = 1; a.pos = n - 6400; a.W = 40; a.HW = 1600; a.s = 16.f; }
  else               { a.lvl = 2; a.pos = n - 8000; a.W = 20; a.HW = 400;  a.s = 32.f; }
  int px = a.pos % a.W, py = a.pos / a.W;
  a.ax = (px + 0.5f) * a.s;
  a.ay = (py + 0.5f) * a.s;
  return a;
}

__device__ __forceinline__ const float* lvl_ptr(const float* p0, const float* p1,
                                                const float* p2, int lvl) {
  return lvl == 0 ? p0 : (lvl == 1 ? p1 : p2);
}

__device__ __forceinline__ float iou_xyxy(float4 a, float4 b) {
  float ix = fmaxf(fminf(a.z, b.z) - fmaxf(a.x, b.x), 0.f);
  float iy = fmaxf(fminf(a.w, b.w) - fmaxf(a.y, b.y), 0.f);
  float inter = ix * iy;
  float w1 = fmaxf(a.z - a.x, 0.f), h1 = fmaxf(a.w - a.y, 0.f);
  float w2 = fmaxf(b.z - b.x, 0.f), h2 = fmaxf(b.w - b.y, 0.f);
  float uni = w1 * h1 + w2 * h2 - inter + 1e-7f;
  return inter / uni;
}

__device__ __forceinline__ float ciou_xyxy(float4 a, float4 b) {
  const float eps = 1e-7f;
  float ix = fmaxf(fminf(a.z, b.z) - fmaxf(a.x, b.x), 0.f);
  float iy = fmaxf(fminf(a.w, b.w) - fmaxf(a.y, b.y), 0.f);
  float inter = ix * iy;
  float w1 = fmaxf(a.z - a.x, 0.f), h1 = fmaxf(a.w - a.y, 0.f);
  float w2 = fmaxf(b.z - b.x, 0.f), h2 = fmaxf(b.w - b.y, 0.f);
  float uni = w1 * h1 + w2 * h2 - inter + eps;
  float iou = inter / uni;
  float cx1 = (a.x + a.z) * 0.5f, cy1 = (a.y + a.w) * 0.5f;
  float cx2 = (b.x + b.z) * 0.5f, cy2 = (b.y + b.w) * 0.5f;
  float rho2 = (cx2 - cx1) * (cx2 - cx1) + (cy2 - cy1) * (cy2 - cy1);
  float cw = fmaxf(a.z, b.z) - fminf(a.x, b.x);
  float ch = fmaxf(a.w, b.w) - fminf(a.y, b.y);
  float c2 = cw * cw + ch * ch + eps;
  const float kpi = 4.f / (float)(M_PI * M_PI);
  float dat = atanf(w2 / (h2 + eps)) - atanf(w1 / (h1 + eps));
  float v = kpi * dat * dat;
  float alpha = v / (1.f - iou + v + eps);
  return iou - (rho2 / c2 + alpha * v);
}

__device__ __forceinline__ float block_sum256(float v) {
  __shared__ float sm[4];
  #pragma unroll
  for (int off = 32; off; off >>= 1) v += __shfl_xor(v, off);
  __syncthreads();
  if ((threadIdx.x & 63) == 0) sm[threadIdx.x >> 6] = v;
  __syncthreads();
  return (threadIdx.x == 0) ? (sm[0] + sm[1] + sm[2] + sm[3]) : 0.f;
}

// --- K0: zero the accumulators ---------------------------------------------
__global__ void k_zero(double* accum) {
  if (threadIdx.x < 8) accum[threadIdx.x] = 0.0;
}

// --- A1: BCE base term — pure float4 stream over the contiguous cls planes --
// cls channels 64..143 are contiguous per (b,level): per-b 168000 float4 units
// (lvl0:128000, lvl1:32000, lvl2:8000). 2625 blocks x 256 thr x 4 units.
__global__ __launch_bounds__(256) void k_bce(
    const float* __restrict__ p0, const float* __restrict__ p1, const float* __restrict__ p2,
    double* __restrict__ accum) {
  int i = blockIdx.x * 256 + threadIdx.x;   // 0 .. 671999
  float lb = 0.f;
  #pragma unroll
  for (int j = 0; j < 4; ++j) {
    int u = i + j * 672000;                 // < 2688000
    int b = u / 168000;
    int r = u % 168000;
    const float4* src;
    if (r < 128000)      src = (const float4*)p0 + ((size_t)(b * NCH + RCH) * 1600 + r);
    else if (r < 160000) src = (const float4*)p1 + ((size_t)(b * NCH + RCH) * 400 + (r - 128000));
    else                 src = (const float4*)p2 + ((size_t)(b * NCH + RCH) * 100 + (r - 160000));
    float4 z4 = *src;
    lb += fmaxf(z4.x, 0.f) + __logf(1.f + __expf(-fabsf(z4.x)));
    lb += fmaxf(z4.y, 0.f) + __logf(1.f + __expf(-fabsf(z4.y)));
    lb += fmaxf(z4.z, 0.f) + __logf(1.f + __expf(-fabsf(z4.z)));
    lb += fmaxf(z4.w, 0.f) + __logf(1.f + __expf(-fabsf(z4.w)));
  }
  float tot = block_sum256(lb);
  if (threadIdx.x == 0) atomicAdd(&accum[0], (double)tot);
}

// --- A2: decode pred boxes, one thread per (anchor, side) -------------------
__global__ __launch_bounds__(256) void k_pbox(
    const float* __restrict__ p0, const float* __restrict__ p1, const float* __restrict__ p2,
    float* __restrict__ pboxf, unsigned long long* __restrict__ slots) {
  int i = blockIdx.x * 256 + threadIdx.x;   // exact: 525*256 == 16*8400
  int q = blockIdx.y;                       // side 0..3
  int b = i / NANCH, n = i % NANCH;
  AInfo A = anchor_of(n);
  const float* p = lvl_ptr(p0, p1, p2, A.lvl);
  size_t base = (size_t)b * NCH * A.HW + A.pos;

  float z[16]; float zm = -1e30f;
  #pragma unroll
  for (int j = 0; j < 16; ++j) {
    z[j] = p[base + (size_t)(q * 16 + j) * A.HW];
    zm = fmaxf(zm, z[j]);
  }
  float se = 0.f, ae = 0.f;
  #pragma unroll
  for (int j = 0; j < 16; ++j) {
    float e = __expf(z[j] - zm);
    se += e; ae += e * (float)j;
  }
  float d = ae / se * A.s;
  float val = (q == 0) ? A.ax - d : (q == 1) ? A.ay - d : (q == 2) ? A.ax + d : A.ay + d;
  pboxf[(size_t)i * 4 + q] = val;
  if (q == 0) slots[i] = 0ULL;
}

// --- B: per-(b,gt) candidate enumeration + top-10 + fused scatter -----------
__global__ __launch_bounds__(256) void k_topk(
    const float* __restrict__ p0, const float* __restrict__ p1, const float* __restrict__ p2,
    const float4* __restrict__ pbox, const float* __restrict__ gtb, const int* __restrict__ gtl,
    float* __restrict__ metric_max, unsigned long long* __restrict__ slots) {
  __shared__ float val[MAXC];
  __shared__ int   idx[MAXC];
  __shared__ float cio[MAXC];
  __shared__ float rv[4];
  __shared__ int   ri[4], rs[4], sdone[1];
  int b = blockIdx.x >> 5, m = blockIdx.x & 31;
  int tid = threadIdx.x;
  float4 g = ((const float4*)gtb)[b * MGT + m];
  int gl = min(max(gtl[b * MGT + m], 0), NCLS - 1);

  const int   Ws[3] = {80, 40, 20};
  const float ss[3] = {8.f, 16.f, 32.f};
  const int   nb[3] = {0, 6400, 8000};
  int x0[3], y0[3], nxl[3], nyl[3], cb[3];
  int cnt = 0;
  #pragma unroll
  for (int L = 0; L < 3; ++L) {
    float s = ss[L]; int W = Ws[L];
    int ax0 = max((int)floorf(g.x / s - 0.5f), 0);        // widened by 1 low side
    int ax1 = min((int)ceilf (g.z / s - 0.5f), W - 1);    // widened by 1 high side
    int ay0 = max((int)floorf(g.y / s - 0.5f), 0);
    int ay1 = min((int)ceilf (g.w / s - 0.5f), W - 1);
    int nx = max(ax1 - ax0 + 1, 0);
    int ny = max(ay1 - ay0 + 1, 0);
    x0[L] = ax0; y0[L] = ay0; nxl[L] = nx; nyl[L] = ny;
    cb[L] = cnt; cnt += nx * ny;
  }
  int C = min(cnt, MAXC);

  for (int t = tid; t < C; t += 256) {
    int L = (t >= cb[2]) ? 2 : (t >= cb[1]) ? 1 : 0;
    int r = t - cb[L];
    int ix = r % nxl[L], iy = r / nxl[L];
    int px = x0[L] + ix, py = y0[L] + iy;
    float ax = (px + 0.5f) * ss[L], ay = (py + 0.5f) * ss[L];
    float al = -3e38f, iou = 0.f; int n = 0x7fffffff;
    if (ax > g.x && ay > g.y && ax < g.z && ay < g.w) {   // exact strict in_gts recheck
      n = nb[L] + py * Ws[L] + px;
      iou = iou_xyxy(pbox[(size_t)b * NANCH + n], g);
      int HW = (L == 0) ? 6400 : (L == 1) ? 1600 : 400;
      const float* p = lvl_ptr(p0, p1, p2, L);
      float z = p[(size_t)b * NCH * HW + (size_t)(RCH + gl) * HW + (py * Ws[L] + px)];
      float sg = 1.f / (1.f + __expf(-z));
      float i3 = iou * iou * iou;
      al = sqrtf(sg) * i3 * i3;
    }
    val[t] = al; idx[t] = n; cio[t] = iou;
  }
  __syncthreads();

  float mmax = -1.f;
  for (int k = 0; k < TOPKK; ++k) {
    float bv = -3e38f; int bn = 0x7fffffff, bs = 0;
    for (int t = tid; t < C; t += 256) {
      float v = val[t]; int n2 = idx[t];
      if (v > bv || (v == bv && n2 < bn)) { bv = v; bn = n2; bs = t; }
    }
    #pragma unroll
    for (int off = 32; off; off >>= 1) {
      float ov = __shfl_xor(bv, off);
      int   on = __shfl_xor(bn, off);
      int   os = __shfl_xor(bs, off);
      if (ov > bv || (ov == bv && on < bn)) { bv = ov; bn = on; bs = os; }
    }
    if ((tid & 63) == 0) { rv[tid >> 6] = bv; ri[tid >> 6] = bn; rs[tid >> 6] = bs; }
    __syncthreads();
    if (tid == 0) {
      #pragma unroll
      for (int w = 1; w < 4; ++w)
        if (rv[w] > bv || (rv[w] == bv && ri[w] < bn)) { bv = rv[w]; bn = ri[w]; bs = rs[w]; }
      if (bv >= 0.f) {          // valid <=> in_gts (align >= 0 for in-box)
        mmax = fmaxf(mmax, bv);
        // iou >= 0: float bits order-preserving; tie prefers smaller m (bigger 31-m)
        unsigned long long key = (1ULL << 62) |
                                 ((unsigned long long)__float_as_uint(cio[bs]) << 6) |
                                 (unsigned long long)(31 - m);
        atomicMax(&slots[(size_t)b * NANCH + bn], key);
        val[bs] = -3e38f;       // remove winner
        sdone[0] = 0;
      } else sdone[0] = 1;
    }
    __syncthreads();
    if (sdone[0]) break;
  }
  if (tid == 0) metric_max[b * MGT + m] = fmaxf(mmax, 1e-9f);
}

// --- D: fg-anchor losses: score, bce correction, ciou, dfl -----------------
__global__ __launch_bounds__(256) void k_final(
    const float* __restrict__ p0, const float* __restrict__ p1, const float* __restrict__ p2,
    const float4* __restrict__ pbox, const float* __restrict__ gtb, const int* __restrict__ gtl,
    const float* __restrict__ metric_max, const unsigned long long* __restrict__ slots,
    double* __restrict__ accum) {
  int i = blockIdx.x * 256 + threadIdx.x;
  unsigned long long key = slots[i];
  float ts_p = 0.f, zc_p = 0.f, box_p = 0.f, dfl_p = 0.f;
  if (key) {
    int b = i / NANCH, n = i % NANCH;
    int m = 31 - (int)(key & 63ULL);
    float iou = __uint_as_float((unsigned int)((key >> 6) & 0xFFFFFFFFULL));
    AInfo A = anchor_of(n);
    float4 g = ((const float4*)gtb)[b * MGT + m];
    int gl = min(max(gtl[b * MGT + m], 0), NCLS - 1);
    const float* p = lvl_ptr(p0, p1, p2, A.lvl);
    size_t base = (size_t)b * NCH * A.HW + A.pos;

    float z = p[base + (size_t)(RCH + gl) * A.HW];
    float sg = 1.f / (1.f + __expf(-z));
    float i3 = iou * iou * iou;
    float align = sqrtf(sg) * i3 * i3;
    float mm = metric_max[b * MGT + m];
    float score = fminf(fmaxf(align / mm * iou, 0.f), 1.f);

    ts_p = score;
    zc_p = z * score;

    float4 pb = pbox[i];
    float ciou = ciou_xyxy(pb, g);
    box_p = (1.f - ciou) * score;

    float inv_s = 1.f / A.s;
    float targ0 = (A.ax - g.x) * inv_s;
    float targ1 = (A.ay - g.y) * inv_s;
    float targ2 = (g.z - A.ax) * inv_s;
    float targ3 = (g.w - A.ay) * inv_s;
    float dfl = 0.f;
    #pragma unroll
    for (int sd = 0; sd < 4; ++sd) {
      float tg = sd == 0 ? targ0 : sd == 1 ? targ1 : sd == 2 ? targ2 : targ3;
      float t = fminf(fmaxf(tg, 0.f), 15.f);
      int left = (int)floorf(t);
      int right = min(left + 1, 15);
      float wl, wr;
      if (right == left) { wl = 1.f; wr = 0.f; }
      else               { wl = (float)right - t; wr = t - (float)left; }
      float zm = -1e30f, zl = 0.f, zr = 0.f;
      float zz[16];
      #pragma unroll
      for (int j = 0; j < 16; ++j) {
        zz[j] = p[base + (size_t)(sd * 16 + j) * A.HW];
        zm = fmaxf(zm, zz[j]);
      }
      float se = 0.f;
      #pragma unroll
      for (int j = 0; j < 16; ++j) {
        se += __expf(zz[j] - zm);
        if (j == left)  zl = zz[j];   // compile-time j vs runtime left -> cndmask
        if (j == right) zr = zz[j];
      }
      float logZ = zm + __logf(se);
      dfl += wl * (logZ - zl) + wr * (logZ - zr);
    }
    dfl_p = dfl * score;
  }
  float s;
  s = block_sum256(ts_p);  if (threadIdx.x == 0 && s != 0.f) atomicAdd(&accum[4], (double)s);
  s = block_sum256(zc_p);  if (threadIdx.x == 0 && s != 0.f) atomicAdd(&accum[1], (double)s);
  s = block_sum256(box_p); if (threadIdx.x == 0 && s != 0.f) atomicAdd(&accum[2], (double)s);
  s = block_sum256(dfl_p); if (threadIdx.x == 0 && s != 0.f) atomicAdd(&accum[3], (double)s);
}

// --- E: combine ------------------------------------------------------------
__global__ void k_out(const double* __restrict__ accum, float* __restrict__ out) {
  double ts = fmax(accum[4], 1.0);
  double loss = 7.5 * accum[2] / ts +
                0.5 * (accum[0] - accum[1]) / ts +
                1.5 * accum[3] / ts;
  out[0] = (float)loss;
}

extern "C" void kernel_launch(void* const* d_in, const int* in_sizes, int n_in,
                              void* d_out, int out_size, void* d_ws, size_t ws_size,
                              hipStream_t stream) {
  const float* p0  = (const float*)d_in[0];
  const float* p1  = (const float*)d_in[1];
  const float* p2  = (const float*)d_in[2];
  const float* gtb = (const float*)d_in[3];
  const int*   gtl = (const int*)d_in[4];
  float* out = (float*)d_out;

  // Workspace layout (bytes, non-overlapping, aligned):
  //   accum      @ 0        : 8 * 8       = 64
  //   metric_max @ 64       : 512 * 4     = 2048    (ends 2112)
  //   pbox       @ 2112     : 134400 * 16 = 2150400 (ends 2152512)  [2112 % 16 == 0]
  //   slots      @ 2152512  : 134400 * 8  = 1075200 (ends 3227712)  [2152512 % 8 == 0]
  char* ws = (char*)d_ws;
  double* accum      = (double*)ws;
  float*  metric_max = (float*)(ws + 64);
  float*  pboxf      = (float*)(ws + 2112);
  float4* pbox       = (float4*)(ws + 2112);
  unsigned long long* slots = (unsigned long long*)(ws + 2152512);

  k_zero<<<1, 64, 0, stream>>>(accum);
  k_bce<<<2625, 256, 0, stream>>>(p0, p1, p2, accum);
  k_pbox<<<dim3(525, 4), 256, 0, stream>>>(p0, p1, p2, pboxf, slots);
  k_topk<<<BATCH * MGT, 256, 0, stream>>>(p0, p1, p2, pbox, gtb, gtl, metric_max, slots);
  k_final<<<(BATCH * NANCH) / 256, 256, 0, stream>>>(p0, p1, p2, pbox, gtb, gtl,
                                                     metric_max, slots, accum);
  k_out<<<1, 1, 0, stream>>>(accum, out);
}

// Round 5
// 149.299 us; speedup vs baseline: 1.5149x; 1.2026x over previous
//
#include <hip/hip_runtime.h>

#define BATCH 16
#define NANCH 8400
#define MGT 32
#define NCLS 80
#define RCH 64
#define NCH 144
#define TOPKK 10
#define MAXC 576    // max in-box candidate cells: <=19^2 + 11^2 + 7^2 = 531
#define PBLK 2100   // pbox blocks: 525 * 4 sides
#define BCEB 2625   // bce blocks
#define TOTB (PBLK + BCEB)

struct AInfo { int lvl, pos, W, HW; float s, ax, ay; };

__device__ __forceinline__ AInfo anchor_of(int n) {
  AInfo a;
  if (n < 6400)      { a.lvl = 0; a.pos = n;        a.W = 80; a.HW = 6400; a.s = 8.f;  }
  else if (n < 8000) { a.lvl = 1; a.pos = n - 6400; a.W = 40; a.HW = 1600; a.s = 16.f; }
  else               { a.lvl = 2; a.pos = n - 8000; a.W = 20; a.HW = 400;  a.s = 32.f; }
  int px = a.pos % a.W, py = a.pos / a.W;
  a.ax = (px + 0.5f) * a.s;
  a.ay = (py + 0.5f) * a.s;
  return a;
}

__device__ __forceinline__ const float* lvl_ptr(const float* p0, const float* p1,
                                                const float* p2, int lvl) {
  return lvl == 0 ? p0 : (lvl == 1 ? p1 : p2);
}

__device__ __forceinline__ float iou_xyxy(float4 a, float4 b) {
  float ix = fmaxf(fminf(a.z, b.z) - fmaxf(a.x, b.x), 0.f);
  float iy = fmaxf(fminf(a.w, b.w) - fmaxf(a.y, b.y), 0.f);
  float inter = ix * iy;
  float w1 = fmaxf(a.z - a.x, 0.f), h1 = fmaxf(a.w - a.y, 0.f);
  float w2 = fmaxf(b.z - b.x, 0.f), h2 = fmaxf(b.w - b.y, 0.f);
  float uni = w1 * h1 + w2 * h2 - inter + 1e-7f;
  return inter / uni;
}

__device__ __forceinline__ float ciou_xyxy(float4 a, float4 b) {
  const float eps = 1e-7f;
  float ix = fmaxf(fminf(a.z, b.z) - fmaxf(a.x, b.x), 0.f);
  float iy = fmaxf(fminf(a.w, b.w) - fmaxf(a.y, b.y), 0.f);
  float inter = ix * iy;
  float w1 = fmaxf(a.z - a.x, 0.f), h1 = fmaxf(a.w - a.y, 0.f);
  float w2 = fmaxf(b.z - b.x, 0.f), h2 = fmaxf(b.w - b.y, 0.f);
  float uni = w1 * h1 + w2 * h2 - inter + eps;
  float iou = inter / uni;
  float cx1 = (a.x + a.z) * 0.5f, cy1 = (a.y + a.w) * 0.5f;
  float cx2 = (b.x + b.z) * 0.5f, cy2 = (b.y + b.w) * 0.5f;
  float rho2 = (cx2 - cx1) * (cx2 - cx1) + (cy2 - cy1) * (cy2 - cy1);
  float cw = fmaxf(a.z, b.z) - fminf(a.x, b.x);
  float ch = fmaxf(a.w, b.w) - fminf(a.y, b.y);
  float c2 = cw * cw + ch * ch + eps;
  const float kpi = 4.f / (float)(M_PI * M_PI);
  float dat = atanf(w2 / (h2 + eps)) - atanf(w1 / (h1 + eps));
  float v = kpi * dat * dat;
  float alpha = v / (1.f - iou + v + eps);
  return iou - (rho2 / c2 + alpha * v);
}

__device__ __forceinline__ float block_sum256(float v) {
  __shared__ float sm[4];
  #pragma unroll
  for (int off = 32; off; off >>= 1) v += __shfl_xor(v, off);
  __syncthreads();
  if ((threadIdx.x & 63) == 0) sm[threadIdx.x >> 6] = v;
  __syncthreads();
  return (threadIdx.x == 0) ? (sm[0] + sm[1] + sm[2] + sm[3]) : 0.f;
}

// --- K1: fused box-decode + logZ cache + BCE base partials + init ----------
__global__ __launch_bounds__(256) void k_fused(
    const float* __restrict__ p0, const float* __restrict__ p1, const float* __restrict__ p2,
    float* __restrict__ pboxf, float* __restrict__ logz,
    unsigned long long* __restrict__ slots, float* __restrict__ bce_part,
    double* __restrict__ accum) {
  int blk = blockIdx.x, tid = threadIdx.x;
  if (blk == 0 && tid < 8) accum[tid] = 0.0;

  if (blk < PBLK) {
    // --- box decode: one thread per (anchor, side) ---
    int q = blk & 3;
    int i = (blk >> 2) * 256 + tid;          // 0 .. 134399
    int b = i / NANCH, n = i % NANCH;
    AInfo A = anchor_of(n);
    const float* p = lvl_ptr(p0, p1, p2, A.lvl);
    size_t base = (size_t)b * NCH * A.HW + A.pos;

    float z[16]; float zm = -1e30f;
    #pragma unroll
    for (int j = 0; j < 16; ++j) {
      z[j] = p[base + (size_t)(q * 16 + j) * A.HW];
      zm = fmaxf(zm, z[j]);
    }
    float se = 0.f, ae = 0.f;
    #pragma unroll
    for (int j = 0; j < 16; ++j) {
      float e = __expf(z[j] - zm);
      se += e; ae += e * (float)j;
    }
    float d = ae / se * A.s;
    float val = (q == 0) ? A.ax - d : (q == 1) ? A.ay - d : (q == 2) ? A.ax + d : A.ay + d;
    pboxf[(size_t)i * 4 + q] = val;
    logz[(size_t)i * 4 + q] = zm + __logf(se);   // log-softmax denominator (raw logits)
    if (q == 0) slots[i] = 0ULL;
  } else {
    // --- BCE base term: contiguous float4 stream over cls planes ---
    int r = blk - PBLK;                      // 0 .. 2624
    int i = r * 256 + tid;                   // 0 .. 671999
    float lb = 0.f;
    #pragma unroll
    for (int j = 0; j < 4; ++j) {
      int u = i + j * 672000;                // < 2688000
      int b = u / 168000;
      int rr = u % 168000;
      const float4* src;
      if (rr < 128000)      src = (const float4*)p0 + ((size_t)(b * NCH + RCH) * 1600 + rr);
      else if (rr < 160000) src = (const float4*)p1 + ((size_t)(b * NCH + RCH) * 400 + (rr - 128000));
      else                  src = (const float4*)p2 + ((size_t)(b * NCH + RCH) * 100 + (rr - 160000));
      float4 z4 = *src;
      lb += fmaxf(z4.x, 0.f) + __logf(1.f + __expf(-fabsf(z4.x)));
      lb += fmaxf(z4.y, 0.f) + __logf(1.f + __expf(-fabsf(z4.y)));
      lb += fmaxf(z4.z, 0.f) + __logf(1.f + __expf(-fabsf(z4.z)));
      lb += fmaxf(z4.w, 0.f) + __logf(1.f + __expf(-fabsf(z4.w)));
    }
    float tot = block_sum256(lb);
    if (tid == 0) bce_part[r] = tot;
  }
}

// --- K2: per-(b,gt) candidate enumeration + top-10 + fused scatter ----------
__global__ __launch_bounds__(256) void k_topk(
    const float* __restrict__ p0, const float* __restrict__ p1, const float* __restrict__ p2,
    const float4* __restrict__ pbox, const float* __restrict__ gtb, const int* __restrict__ gtl,
    float* __restrict__ metric_max, unsigned long long* __restrict__ slots) {
  __shared__ float val[MAXC];
  __shared__ int   idx[MAXC];
  __shared__ float cio[MAXC];
  __shared__ float rv[4];
  __shared__ int   ri[4], rs[4], sdone[1];
  int b = blockIdx.x >> 5, m = blockIdx.x & 31;
  int tid = threadIdx.x;
  float4 g = ((const float4*)gtb)[b * MGT + m];
  int gl = min(max(gtl[b * MGT + m], 0), NCLS - 1);

  const int   Ws[3] = {80, 40, 20};
  const float ss[3] = {8.f, 16.f, 32.f};
  const int   nb[3] = {0, 6400, 8000};
  int x0[3], y0[3], nxl[3], cb[3];
  int cnt = 0;
  #pragma unroll
  for (int L = 0; L < 3; ++L) {
    float s = ss[L]; int W = Ws[L];
    int ax0 = max((int)floorf(g.x / s - 0.5f), 0);        // widened 1 low side
    int ax1 = min((int)ceilf (g.z / s - 0.5f), W - 1);    // widened 1 high side
    int ay0 = max((int)floorf(g.y / s - 0.5f), 0);
    int ay1 = min((int)ceilf (g.w / s - 0.5f), W - 1);
    int nx = max(ax1 - ax0 + 1, 0);
    int ny = max(ay1 - ay0 + 1, 0);
    x0[L] = ax0; y0[L] = ay0; nxl[L] = nx;
    cb[L] = cnt; cnt += nx * ny;
  }
  int C = min(cnt, MAXC);

  for (int t = tid; t < C; t += 256) {
    int L = (t >= cb[2]) ? 2 : (t >= cb[1]) ? 1 : 0;
    int r = t - cb[L];
    int ix = r % nxl[L], iy = r / nxl[L];
    int px = x0[L] + ix, py = y0[L] + iy;
    float ax = (px + 0.5f) * ss[L], ay = (py + 0.5f) * ss[L];
    float al = -3e38f, iou = 0.f; int n = 0x7fffffff;
    if (ax > g.x && ay > g.y && ax < g.z && ay < g.w) {   // exact strict in_gts recheck
      n = nb[L] + py * Ws[L] + px;
      iou = iou_xyxy(pbox[(size_t)b * NANCH + n], g);
      int HW = (L == 0) ? 6400 : (L == 1) ? 1600 : 400;
      const float* p = lvl_ptr(p0, p1, p2, L);
      float z = p[(size_t)b * NCH * HW + (size_t)(RCH + gl) * HW + (py * Ws[L] + px)];
      float sg = 1.f / (1.f + __expf(-z));
      float i3 = iou * iou * iou;
      al = sqrtf(sg) * i3 * i3;
    }
    val[t] = al; idx[t] = n; cio[t] = iou;
  }
  __syncthreads();

  float mmax = -1.f;
  for (int k = 0; k < TOPKK; ++k) {
    float bv = -3e38f; int bn = 0x7fffffff, bs = 0;
    for (int t = tid; t < C; t += 256) {
      float v = val[t]; int n2 = idx[t];
      if (v > bv || (v == bv && n2 < bn)) { bv = v; bn = n2; bs = t; }
    }
    #pragma unroll
    for (int off = 32; off; off >>= 1) {
      float ov = __shfl_xor(bv, off);
      int   on = __shfl_xor(bn, off);
      int   os = __shfl_xor(bs, off);
      if (ov > bv || (ov == bv && on < bn)) { bv = ov; bn = on; bs = os; }
    }
    if ((tid & 63) == 0) { rv[tid >> 6] = bv; ri[tid >> 6] = bn; rs[tid >> 6] = bs; }
    __syncthreads();
    if (tid == 0) {
      #pragma unroll
      for (int w = 1; w < 4; ++w)
        if (rv[w] > bv || (rv[w] == bv && ri[w] < bn)) { bv = rv[w]; bn = ri[w]; bs = rs[w]; }
      if (bv >= 0.f) {          // valid <=> in_gts (align >= 0 for in-box)
        mmax = fmaxf(mmax, bv);
        // iou >= 0: float bits order-preserving; tie prefers smaller m (bigger 31-m)
        unsigned long long key = (1ULL << 62) |
                                 ((unsigned long long)__float_as_uint(cio[bs]) << 6) |
                                 (unsigned long long)(31 - m);
        atomicMax(&slots[(size_t)b * NANCH + bn], key);
        val[bs] = -3e38f;       // remove winner
        sdone[0] = 0;
      } else sdone[0] = 1;
    }
    __syncthreads();
    if (sdone[0]) break;
  }
  if (tid == 0) metric_max[b * MGT + m] = fmaxf(mmax, 1e-9f);
}

// --- K3: fg-anchor losses: score, bce correction, ciou, dfl ----------------
__global__ __launch_bounds__(256) void k_final(
    const float* __restrict__ p0, const float* __restrict__ p1, const float* __restrict__ p2,
    const float4* __restrict__ pbox, const float* __restrict__ logz,
    const float* __restrict__ gtb, const int* __restrict__ gtl,
    const float* __restrict__ metric_max, const unsigned long long* __restrict__ slots,
    double* __restrict__ accum) {
  int i = blockIdx.x * 256 + threadIdx.x;
  unsigned long long key = slots[i];
  float ts_p = 0.f, zc_p = 0.f, box_p = 0.f, dfl_p = 0.f;
  if (key) {
    int b = i / NANCH, n = i % NANCH;
    int m = 31 - (int)(key & 63ULL);
    float iou = __uint_as_float((unsigned int)((key >> 6) & 0xFFFFFFFFULL));
    AInfo A = anchor_of(n);
    float4 g = ((const float4*)gtb)[b * MGT + m];
    int gl = min(max(gtl[b * MGT + m], 0), NCLS - 1);
    const float* p = lvl_ptr(p0, p1, p2, A.lvl);
    size_t base = (size_t)b * NCH * A.HW + A.pos;

    float z = p[base + (size_t)(RCH + gl) * A.HW];
    float sg = 1.f / (1.f + __expf(-z));
    float i3 = iou * iou * iou;
    float align = sqrtf(sg) * i3 * i3;
    float mm = metric_max[b * MGT + m];
    float score = fminf(fmaxf(align / mm * iou, 0.f), 1.f);

    ts_p = score;
    zc_p = z * score;

    float4 pb = pbox[i];
    float ciou = ciou_xyxy(pb, g);
    box_p = (1.f - ciou) * score;

    float4 lz4 = ((const float4*)logz)[i];
    float inv_s = 1.f / A.s;
    float targ0 = (A.ax - g.x) * inv_s;
    float targ1 = (A.ay - g.y) * inv_s;
    float targ2 = (g.z - A.ax) * inv_s;
    float targ3 = (g.w - A.ay) * inv_s;
    float dfl = 0.f;
    #pragma unroll
    for (int sd = 0; sd < 4; ++sd) {
      float tg = sd == 0 ? targ0 : sd == 1 ? targ1 : sd == 2 ? targ2 : targ3;
      float lZ = sd == 0 ? lz4.x : sd == 1 ? lz4.y : sd == 2 ? lz4.z : lz4.w;
      float t = fminf(fmaxf(tg, 0.f), 15.f);
      int left = (int)floorf(t);
      int right = min(left + 1, 15);
      float wl, wr;
      if (right == left) { wl = 1.f; wr = 0.f; }
      else               { wl = (float)right - t; wr = t - (float)left; }
      float zl = p[base + (size_t)(sd * 16 + left)  * A.HW];
      float zr = p[base + (size_t)(sd * 16 + right) * A.HW];
      dfl += wl * (lZ - zl) + wr * (lZ - zr);
    }
    dfl_p = dfl * score;
  }
  float s;
  s = block_sum256(ts_p);  if (threadIdx.x == 0 && s != 0.f) atomicAdd(&accum[4], (double)s);
  s = block_sum256(zc_p);  if (threadIdx.x == 0 && s != 0.f) atomicAdd(&accum[1], (double)s);
  s = block_sum256(box_p); if (threadIdx.x == 0 && s != 0.f) atomicAdd(&accum[2], (double)s);
  s = block_sum256(dfl_p); if (threadIdx.x == 0 && s != 0.f) atomicAdd(&accum[3], (double)s);
}

// --- K4: combine (sums bce partials too) -----------------------------------
__global__ void k_out(const double* __restrict__ accum, const float* __restrict__ bce_part,
                      float* __restrict__ out) {
  int tid = threadIdx.x;
  float s = 0.f;
  for (int t = tid; t < BCEB; t += 256) s += bce_part[t];
  s = block_sum256(s);
  if (tid == 0) {
    double ts = fmax(accum[4], 1.0);
    double loss = 7.5 * accum[2] / ts +
                  0.5 * ((double)s - accum[1]) / ts +
                  1.5 * accum[3] / ts;
    out[0] = (float)loss;
  }
}

extern "C" void kernel_launch(void* const* d_in, const int* in_sizes, int n_in,
                              void* d_out, int out_size, void* d_ws, size_t ws_size,
                              hipStream_t stream) {
  const float* p0  = (const float*)d_in[0];
  const float* p1  = (const float*)d_in[1];
  const float* p2  = (const float*)d_in[2];
  const float* gtb = (const float*)d_in[3];
  const int*   gtl = (const int*)d_in[4];
  float* out = (float*)d_out;

  // Workspace layout (bytes, non-overlapping, aligned):
  //   accum      @ 0        : 8 * 8           = 64
  //   metric_max @ 64       : 512 * 4         = 2048    (ends 2112)
  //   bce_part   @ 2112     : 2625 * 4        = 10500   (ends 12612; pad to 12624)
  //   pbox/pboxf @ 12624    : 134400 * 16     = 2150400 (ends 2163024)  [12624 % 16 == 0]
  //   logz       @ 2163024  : 134400 * 4 * 4  = 2150400 (ends 4313424)  [% 16 == 0]
  //   slots      @ 4313424  : 134400 * 8      = 1075200 (ends 5388624)  [% 8 == 0]
  char* ws = (char*)d_ws;
  double* accum      = (double*)ws;
  float*  metric_max = (float*)(ws + 64);
  float*  bce_part   = (float*)(ws + 2112);
  float*  pboxf      = (float*)(ws + 12624);
  float4* pbox       = (float4*)(ws + 12624);
  float*  logz       = (float*)(ws + 2163024);
  unsigned long long* slots = (unsigned long long*)(ws + 4313424);

  k_fused<<<TOTB, 256, 0, stream>>>(p0, p1, p2, pboxf, logz, slots, bce_part, accum);
  k_topk<<<BATCH * MGT, 256, 0, stream>>>(p0, p1, p2, pbox, gtb, gtl, metric_max, slots);
  k_final<<<(BATCH * NANCH) / 256, 256, 0, stream>>>(p0, p1, p2, pbox, logz, gtb, gtl,
                                                     metric_max, slots, accum);
  k_out<<<1, 256, 0, stream>>>(accum, bce_part, out);
}